// Round 4
// baseline (145.870 us; speedup 1.0000x reference)
//
#include <hip/hip_runtime.h>
#include <math.h>

// Problem constants (fixed by the reference):
#define B_ 4
#define C_ 192
#define L_ 4096
#define CO_ 64
#define LOG2E 1.44269504088896340736f

using half8 = __attribute__((ext_vector_type(8))) _Float16;
using half4v = __attribute__((ext_vector_type(4))) _Float16;
using half2v = __attribute__((ext_vector_type(2))) _Float16;
using fp16x2 = __attribute__((ext_vector_type(2))) __fp16;
using f32x16 = __attribute__((ext_vector_type(16))) float;

__device__ inline half2v pkrtz(float a, float b) {
  return __builtin_bit_cast(half2v, __builtin_amdgcn_cvt_pkrtz(a, b));
}

// ws layout (fully rewritten every call):
//   Wf  : 4 * 64 * 192 f16                          (96 KB)
//   fB  : [b][l][o] f16, PRE-SCALED by log2e        (2 MB)  A-operand for S
//   gB  : [b][m][o] f16                             (2 MB)  B-operand for S
//   hB  : [b][o][l] f16                             (2 MB)  A-operand for O
//   v1N : [b][o][l] f32                             (4 MB)  epilogue add

union U32H2 { int i; half2v h; };
__device__ inline half2v shfl32(half2v v) {
  U32H2 u; u.h = v;
  u.i = __shfl_xor(u.i, 32, 64);
  return u.h;
}

// Kernel 0: weights fp32 -> f16.
__global__ void wcvt_kernel(const float* __restrict__ Wq,
                            const float* __restrict__ Wk,
                            const float* __restrict__ Wv,
                            const float* __restrict__ Wv1,
                            _Float16* __restrict__ Wf) {
  const float* src = (blockIdx.y == 0) ? Wq
                     : (blockIdx.y == 1) ? Wk
                     : (blockIdx.y == 2) ? Wv : Wv1;
  const int idx = (blockIdx.x * 256 + threadIdx.x) * 4;
  if (idx < CO_ * C_) {
    const float4 v = *(const float4*)(src + idx);
    half4v h;
    h[0] = (_Float16)v.x; h[1] = (_Float16)v.y;
    h[2] = (_Float16)v.z; h[3] = (_Float16)v.w;
    *(half4v*)(Wf + (size_t)blockIdx.y * CO_ * C_ + idx) = h;
  }
}

// ---------------------------------------------------------------------------
// Kernel 1: projections via MFMA.  Grid (L/32, B), 256 thr (4 waves).
// x tile staged f32 [c][l] (natural layout) via global_load_lds width=16.
// B-frags: conflict-free stride-32-dword LDS column reads + cvt_pkrtz.
// Wave w owns projection w; 2 o-halves x 12 k-steps of 32x32x16 MFMA.
// ---------------------------------------------------------------------------
__global__ __launch_bounds__(256) void proj_mfma(
    const float* __restrict__ x, const _Float16* __restrict__ Wf,
    _Float16* __restrict__ fB, _Float16* __restrict__ gB,
    _Float16* __restrict__ hB, float* __restrict__ v1N) {
  __shared__ __align__(16) float xs[C_ * 32];  // [c][l], rows of 128 B
  const int b = blockIdx.y, l0 = blockIdx.x * 32;
  const int t = threadIdx.x;
  const int lane = t & 63, w = t >> 6;
  const int m = lane & 31, hi = lane >> 5;

  {  // stage: wave w loads c-range [48w, 48w+48), 8 c-rows (1 KB) per dma
    const float* xb = x + (size_t)b * C_ * L_ + l0;
    const int c0 = w * 48;
#pragma unroll
    for (int i = 0; i < 6; ++i) {
      const int cc = c0 + i * 8;
      const float* gp = xb + (size_t)(cc + (lane >> 3)) * L_ + (lane & 7) * 4;
      __builtin_amdgcn_global_load_lds(
          (const __attribute__((address_space(1))) void*)gp,
          (__attribute__((address_space(3))) void*)&xs[cc * 32], 16, 0, 0);
    }
  }
  __syncthreads();

  const _Float16* Wp = Wf + (size_t)w * CO_ * C_;
  const int lg = l0 + m;  // global l column this lane owns (C-layout col)
  for (int oh = 0; oh < 2; ++oh) {
    const _Float16* wr = Wp + (size_t)(32 * oh + m) * C_ + hi * 8;
    half8 aF[12];
#pragma unroll
    for (int ks = 0; ks < 12; ++ks) aF[ks] = *(const half8*)(wr + ks * 16);
    f32x16 acc = {};
#pragma unroll
    for (int ks = 0; ks < 12; ++ks) {
      const float* xr = &xs[(16 * ks + 8 * hi) * 32 + m];
      half8 bF;
#pragma unroll
      for (int e = 0; e < 8; e += 2) {
        const half2v hp = pkrtz(xr[e * 32], xr[(e + 1) * 32]);
        bF[e] = hp[0];
        bF[e + 1] = hp[1];
      }
      acc = __builtin_amdgcn_mfma_f32_32x32x16_f16(aF[ks], bF, acc, 0, 0, 0);
    }
    if (w < 2) {
      // fB/gB: [b][l][o] f16.  fB pre-scaled by log2e (exp2-domain softmax).
      const float sc = (w == 0) ? LOG2E : 1.0f;
      _Float16* dst = (w == 0 ? fB : gB) + ((size_t)b * L_ + lg) * CO_;
#pragma unroll
      for (int r = 0; r < 16; r += 2) {
        const int o = 32 * oh + 4 * hi + 8 * (r >> 2) + (r & 3);
        const half2v h2 = pkrtz(acc[r] * sc, acc[r + 1] * sc);
        *(half2v*)(dst + o) = h2;
      }
    } else if (w == 2) {
#pragma unroll
      for (int r = 0; r < 16; ++r) {
        const int o = 32 * oh + 4 * hi + 8 * (r >> 2) + (r & 3);
        hB[((size_t)b * CO_ + o) * L_ + lg] = (_Float16)acc[r];
      }
    } else {
#pragma unroll
      for (int r = 0; r < 16; ++r) {
        const int o = 32 * oh + 4 * hi + 8 * (r >> 2) + (r & 3);
        v1N[((size_t)b * CO_ + o) * L_ + lg] = acc[r];
      }
    }
  }
}

// ---------------------------------------------------------------------------
// Kernel 2: flash attention, f16 MFMA, exp2-domain softmax.
// 512 blocks (1D, XCD-aware decode: id&7 -> batch pair, so each XCD's L2
// holds one batch's 1 MB working set), 512 thr = 8 waves (4 waves/SIMD).
// Wave s owns l-partition [512s, 512s+512), 16 steps of 32 l.
// P (S's C-layout) -> O's B-operand layout entirely in-register via
// shfl_xor(32) + cndmask: no LDS in the main loop, no bank conflicts.
// ---------------------------------------------------------------------------
__global__ __launch_bounds__(512, 4) void attn_mfma(
    const _Float16* __restrict__ fB, const _Float16* __restrict__ gB,
    const _Float16* __restrict__ hB, const float* __restrict__ v1N,
    const float* __restrict__ gamma_p, float* __restrict__ out) {
  __shared__ float obuf4[4][CO_][33];
  __shared__ float redM[8][32];
  __shared__ float redZ[8][32];

  const int id = blockIdx.x;
  const int b = (id >> 1) & 3;                 // XCD pair -> batch
  const int mt = ((id & 1) << 6) | (id >> 3);  // 0..127
  const int m0 = mt * 32;
  const int t = threadIdx.x;
  const int lane = t & 63, s = t >> 6;
  const int m = lane & 31, hi = lane >> 5;

  const _Float16* fBase = fB + (size_t)b * L_ * CO_;
  const _Float16* hBase = hB + (size_t)b * CO_ * L_;

  // loop-invariant g B-frags: B[k=o][n=m]
  const _Float16* gRow = gB + ((size_t)b * L_ + m0 + m) * CO_ + hi * 8;
  half8 gf[4];
#pragma unroll
  for (int ks = 0; ks < 4; ++ks) gf[ks] = *(const half8*)(gRow + ks * 16);

  f32x16 o0 = {}, o1 = {};
  float mx = -INFINITY, Z = 0.f;

  for (int stp = 0; stp < 16; ++stp) {
    const int lb = s * 512 + stp * 32;
    // S = f^T g (scores already in log2 units via fB pre-scale)
    const _Float16* fRow = fBase + (size_t)(lb + m) * CO_ + hi * 8;
    f32x16 S = {};
#pragma unroll
    for (int ks = 0; ks < 4; ++ks) {
      const half8 aF = *(const half8*)(fRow + ks * 16);
      S = __builtin_amdgcn_mfma_f32_32x32x16_f16(aF, gf[ks], S, 0, 0, 0);
    }
    // online softmax; rescale only when the max actually moves
    float tmax = S[0];
#pragma unroll
    for (int r = 1; r < 16; ++r) tmax = fmaxf(tmax, S[r]);
    tmax = fmaxf(tmax, __shfl_xor(tmax, 32, 64));
    if (__any(tmax > mx)) {
      const float mnew = fmaxf(mx, tmax);
      const float corr = exp2f(mx - mnew);  // exp2(-inf)=0 on first step
      mx = mnew;
      Z *= corr;
#pragma unroll
      for (int r = 0; r < 16; ++r) { o0[r] *= corr; o1[r] *= corr; }
    }
    half2v q[8];
    float zl = 0.f;
#pragma unroll
    for (int j = 0; j < 8; ++j) {
      const float p0 = exp2f(S[2 * j] - mx);
      const float p1 = exp2f(S[2 * j + 1] - mx);
      zl += p0 + p1;
      q[j] = pkrtz(p0, p1);
    }
    Z += zl;  // per-half partial; cross-half shfl deferred to after loop
    // C-layout -> B-operand layout, in-register (lane ^ 32 exchange)
    half2v sq[8];
#pragma unroll
    for (int j = 0; j < 8; ++j) sq[j] = shfl32(q[j]);
    const bool h1 = (hi != 0);
    const half2v c0 = h1 ? sq[2] : q[0];
    const half2v c1 = h1 ? sq[3] : q[1];
    const half2v c2 = h1 ? q[2] : sq[0];
    const half2v c3 = h1 ? q[3] : sq[1];
    const half2v c4 = h1 ? sq[6] : q[4];
    const half2v c5 = h1 ? sq[7] : q[5];
    const half2v c6 = h1 ? q[6] : sq[4];
    const half2v c7 = h1 ? q[7] : sq[5];
    half8 bP0, bP1;
    bP0[0] = c0[0]; bP0[1] = c0[1]; bP0[2] = c1[0]; bP0[3] = c1[1];
    bP0[4] = c2[0]; bP0[5] = c2[1]; bP0[6] = c3[0]; bP0[7] = c3[1];
    bP1[0] = c4[0]; bP1[1] = c4[1]; bP1[2] = c5[0]; bP1[3] = c5[1];
    bP1[4] = c6[0]; bP1[5] = c6[1]; bP1[6] = c7[0]; bP1[7] = c7[1];
    // O += h P
    const _Float16* hRow = hBase + (size_t)m * L_ + lb + hi * 8;
    const _Float16* hRow2 = hBase + (size_t)(32 + m) * L_ + lb + hi * 8;
    o0 = __builtin_amdgcn_mfma_f32_32x32x16_f16(*(const half8*)(hRow), bP0, o0, 0, 0, 0);
    o1 = __builtin_amdgcn_mfma_f32_32x32x16_f16(*(const half8*)(hRow2), bP0, o1, 0, 0, 0);
    o0 = __builtin_amdgcn_mfma_f32_32x32x16_f16(*(const half8*)(hRow + 16), bP1, o0, 0, 0, 0);
    o1 = __builtin_amdgcn_mfma_f32_32x32x16_f16(*(const half8*)(hRow2 + 16), bP1, o1, 0, 0, 0);
  }

  // ---- merge the 8 l-partitions ----
  Z += __shfl_xor(Z, 32, 64);
  redM[s][m] = mx;  // both halves hold identical mx
  redZ[s][m] = Z;
  __syncthreads();
  float M = redM[0][m];
#pragma unroll
  for (int i = 1; i < 8; ++i) M = fmaxf(M, redM[i][m]);
  float Zt = 0.f;
#pragma unroll
  for (int i = 0; i < 8; ++i) Zt += exp2f(redM[i][m] - M) * redZ[i][m];
  const float sc = exp2f(mx - M);
  if (s < 4) {
#pragma unroll
    for (int r = 0; r < 16; ++r) {
      const int o = 4 * hi + 8 * (r >> 2) + (r & 3);
      obuf4[s][o][m] = sc * o0[r];
      obuf4[s][o + 32][m] = sc * o1[r];
    }
  }
  __syncthreads();
  if (s >= 4) {
#pragma unroll
    for (int r = 0; r < 16; ++r) {
      const int o = 4 * hi + 8 * (r >> 2) + (r & 3);
      obuf4[s - 4][o][m] += sc * o0[r];
      obuf4[s - 4][o + 32][m] += sc * o1[r];
    }
  }
  __syncthreads();

  // epilogue: out = gamma * O / Zt + v1   (Zt is for column m = t&31)
  const float gam = gamma_p[0];
  const float inv = 1.0f / Zt;
  const int me = t & 31;
  const int ob = t >> 5;  // 0..15
#pragma unroll
  for (int i = 0; i < 4; ++i) {
    const int o = ob + 16 * i;
    const float val = obuf4[0][o][me] + obuf4[1][o][me] +
                      obuf4[2][o][me] + obuf4[3][o][me];
    const size_t g = ((size_t)b * CO_ + o) * L_ + m0 + me;
    out[g] = gam * val * inv + v1N[g];
  }
}

extern "C" void kernel_launch(void* const* d_in, const int* in_sizes, int n_in,
                              void* d_out, int out_size, void* d_ws,
                              size_t ws_size, hipStream_t stream) {
  const float* x = (const float*)d_in[0];
  const float* Wq = (const float*)d_in[1];
  const float* Wk = (const float*)d_in[2];
  const float* Wv = (const float*)d_in[3];
  const float* Wv1 = (const float*)d_in[4];
  const float* gamma = (const float*)d_in[5];
  float* out = (float*)d_out;

  _Float16* Wf = (_Float16*)d_ws;
  _Float16* fB = Wf + (size_t)4 * CO_ * C_;
  _Float16* gB = fB + (size_t)B_ * L_ * CO_;
  _Float16* hB = gB + (size_t)B_ * L_ * CO_;
  float* v1N = (float*)(hB + (size_t)B_ * L_ * CO_);

  wcvt_kernel<<<dim3(12, 4), 256, 0, stream>>>(Wq, Wk, Wv, Wv1, Wf);
  proj_mfma<<<dim3(L_ / 32, B_), 256, 0, stream>>>(x, Wf, fB, gB, hB, v1N);
  attn_mfma<<<512, 512, 0, stream>>>(fB, gB, hB, v1N, gamma, out);
}

// Round 5
// 118.662 us; speedup vs baseline: 1.2293x; 1.2293x over previous
//
#include <hip/hip_runtime.h>
#include <math.h>

// Problem constants (fixed by the reference):
#define B_ 4
#define C_ 192
#define L_ 4096
#define CO_ 64
#define LOG2E 1.44269504088896340736f

using half8 = __attribute__((ext_vector_type(8))) _Float16;
using half4v = __attribute__((ext_vector_type(4))) _Float16;
using half2v = __attribute__((ext_vector_type(2))) _Float16;
using f32x16 = __attribute__((ext_vector_type(16))) float;

#if __has_builtin(__builtin_amdgcn_exp2f)
#define EXP2(x) __builtin_amdgcn_exp2f(x)
#else
#define EXP2(x) exp2f(x)
#endif

__device__ inline half2v pkrtz(float a, float b) {
  return __builtin_bit_cast(half2v, __builtin_amdgcn_cvt_pkrtz(a, b));
}

union U32H2 { int i; half2v h; };
__device__ inline half2v shfl32(half2v v) {
  U32H2 u; u.h = v;
  u.i = __shfl_xor(u.i, 32, 64);
  return u.h;
}

// ws layout (fully rewritten every call):
//   Wf  : 4 * 64 * 192 f16  (Wq pre-scaled by log2e)
//   fB  : [b][l][o] f16  (2 MB)  A-operand for S (holds log2e * f)
//   gB  : [b][m][o] f16  (2 MB)  B-operand for S
//   hB  : [b][o][l] f16  (2 MB)  A-operand for O
//   v1N : [b][o][l] f32  (4 MB)  epilogue add

// Kernel 0: weights fp32 -> f16 (Wq scaled by log2e for exp2-domain softmax).
__global__ void wcvt_kernel(const float* __restrict__ Wq,
                            const float* __restrict__ Wk,
                            const float* __restrict__ Wv,
                            const float* __restrict__ Wv1,
                            _Float16* __restrict__ Wf) {
  const float* src = (blockIdx.y == 0) ? Wq
                     : (blockIdx.y == 1) ? Wk
                     : (blockIdx.y == 2) ? Wv : Wv1;
  const float s = (blockIdx.y == 0) ? LOG2E : 1.0f;
  const int idx = (blockIdx.x * 256 + threadIdx.x) * 4;
  if (idx < CO_ * C_) {
    const float4 v = *(const float4*)(src + idx);
    half4v h;
    h[0] = (_Float16)(v.x * s); h[1] = (_Float16)(v.y * s);
    h[2] = (_Float16)(v.z * s); h[3] = (_Float16)(v.w * s);
    *(half4v*)(Wf + (size_t)blockIdx.y * CO_ * C_ + idx) = h;
  }
}

// ---------------------------------------------------------------------------
// Kernel 1: projections via MFMA.  Grid (L/32, B), 256 thr (4 waves).
// x staged f32 [c][l] via global_load_lds width=16.
// Waves 0,1 (f,g): OPERAND-SWAPPED — D[l][o] = sum_c x^T[l][c] W^T[c][o];
//   C-layout columns are o -> stores to [b][l][o] are coalesced 2-B stores.
// Waves 2,3 (h,v1): D[o][l]; C-layout columns are l -> coalesced as before.
// ---------------------------------------------------------------------------
__global__ __launch_bounds__(256) void proj_mfma(
    const float* __restrict__ x, const _Float16* __restrict__ Wf,
    _Float16* __restrict__ fB, _Float16* __restrict__ gB,
    _Float16* __restrict__ hB, float* __restrict__ v1N) {
  __shared__ __align__(16) float xs[C_ * 32];  // [c][l], rows of 128 B
  const int b = blockIdx.y, l0 = blockIdx.x * 32;
  const int t = threadIdx.x;
  const int lane = t & 63, w = t >> 6;
  const int m = lane & 31, hi = lane >> 5;

  {  // stage: wave w loads c-range [48w, 48w+48)
    const float* xb = x + (size_t)b * C_ * L_ + l0;
    const int c0 = w * 48;
#pragma unroll
    for (int i = 0; i < 6; ++i) {
      const int cc = c0 + i * 8;
      const float* gp = xb + (size_t)(cc + (lane >> 3)) * L_ + (lane & 7) * 4;
      __builtin_amdgcn_global_load_lds(
          (const __attribute__((address_space(1))) void*)gp,
          (__attribute__((address_space(3))) void*)&xs[cc * 32], 16, 0, 0);
    }
  }
  __syncthreads();

  const _Float16* Wp = Wf + (size_t)w * CO_ * C_;
  if (w < 2) {
    // A-frag (x^T): lane row l=m, k-half hi; B-frag (W^T): lane col o=m.
    f32x16 acc0 = {}, acc1 = {};
#pragma unroll
    for (int ks = 0; ks < 12; ++ks) {
      const float* xr = &xs[(ks * 16 + hi * 8) * 32 + m];
      half8 aF;
#pragma unroll
      for (int e = 0; e < 8; e += 2) {
        const half2v hp = pkrtz(xr[e * 32], xr[(e + 1) * 32]);
        aF[e] = hp[0]; aF[e + 1] = hp[1];
      }
      const half8 b0 = *(const half8*)(Wp + (size_t)m * C_ + ks * 16 + hi * 8);
      const half8 b1 =
          *(const half8*)(Wp + (size_t)(32 + m) * C_ + ks * 16 + hi * 8);
      acc0 = __builtin_amdgcn_mfma_f32_32x32x16_f16(aF, b0, acc0, 0, 0, 0);
      acc1 = __builtin_amdgcn_mfma_f32_32x32x16_f16(aF, b1, acc1, 0, 0, 0);
    }
    _Float16* dst = (w == 0) ? fB : gB;
#pragma unroll
    for (int r = 0; r < 16; ++r) {
      const int lrow = 4 * hi + 8 * (r >> 2) + (r & 3);
      _Float16* row = dst + ((size_t)b * L_ + l0 + lrow) * CO_;
      row[m] = (_Float16)acc0[r];        // o = m        (coalesced)
      row[32 + m] = (_Float16)acc1[r];   // o = 32 + m
    }
  } else {
    // D[o][l]: A = W rows, B = x cols (as round 4) — stores already coalesced.
    const int lg = l0 + m;
    for (int oh = 0; oh < 2; ++oh) {
      const _Float16* wr = Wp + (size_t)(32 * oh + m) * C_ + hi * 8;
      f32x16 acc = {};
#pragma unroll
      for (int ks = 0; ks < 12; ++ks) {
        const float* xr = &xs[(16 * ks + 8 * hi) * 32 + m];
        half8 bF;
#pragma unroll
        for (int e = 0; e < 8; e += 2) {
          const half2v hp = pkrtz(xr[e * 32], xr[(e + 1) * 32]);
          bF[e] = hp[0]; bF[e + 1] = hp[1];
        }
        const half8 aF = *(const half8*)(wr + ks * 16);
        acc = __builtin_amdgcn_mfma_f32_32x32x16_f16(aF, bF, acc, 0, 0, 0);
      }
      if (w == 2) {
#pragma unroll
        for (int r = 0; r < 16; ++r) {
          const int o = 32 * oh + 4 * hi + 8 * (r >> 2) + (r & 3);
          hB[((size_t)b * CO_ + o) * L_ + lg] = (_Float16)acc[r];
        }
      } else {
#pragma unroll
        for (int r = 0; r < 16; ++r) {
          const int o = 32 * oh + 4 * hi + 8 * (r >> 2) + (r & 3);
          v1N[((size_t)b * CO_ + o) * L_ + lg] = acc[r];
        }
      }
    }
  }
}

// ---------------------------------------------------------------------------
// Kernel 2: flash attention, 64-m wave tile, register-prefetched.
// 256 blocks (1/CU; id&7 -> XCD pair -> batch), 512 thr = 8 waves.
// Wave s: l-partition [512s, 512s+512), 16 steps of 32 l x 64 m.
// Per step: 8 S-MFMA + 2x softmax + 8 O-MFMA; f/h frags double-buffered
// in registers (prefetch issued before compute).  No LDS in main loop.
// ---------------------------------------------------------------------------
__device__ __forceinline__ void softmax_o(const f32x16& S, float& mx, float& Z,
                                          f32x16& oa, f32x16& ob,
                                          const half8* hc, bool h1) {
  float tmax = S[0];
#pragma unroll
  for (int r = 1; r < 16; ++r) tmax = fmaxf(tmax, S[r]);
  tmax = fmaxf(tmax, __shfl_xor(tmax, 32, 64));
  if (__any(tmax > mx)) {
    const float mnew = fmaxf(mx, tmax);
    const float corr = EXP2(mx - mnew);
    mx = mnew;
    Z *= corr;
#pragma unroll
    for (int r = 0; r < 16; ++r) { oa[r] *= corr; ob[r] *= corr; }
  }
  half2v q[8];
  float zl = 0.f;
#pragma unroll
  for (int j = 0; j < 8; ++j) {
    const float p0 = EXP2(S[2 * j] - mx);
    const float p1 = EXP2(S[2 * j + 1] - mx);
    zl += p0 + p1;
    q[j] = pkrtz(p0, p1);
  }
  Z += zl;  // per-half partial; cross-half shfl deferred to merge
  half2v sq[8];
#pragma unroll
  for (int j = 0; j < 8; ++j) sq[j] = shfl32(q[j]);
  const half2v c0 = h1 ? sq[2] : q[0];
  const half2v c1 = h1 ? sq[3] : q[1];
  const half2v c2 = h1 ? q[2] : sq[0];
  const half2v c3 = h1 ? q[3] : sq[1];
  const half2v c4 = h1 ? sq[6] : q[4];
  const half2v c5 = h1 ? sq[7] : q[5];
  const half2v c6 = h1 ? q[6] : sq[4];
  const half2v c7 = h1 ? q[7] : sq[5];
  half8 bP0, bP1;
  bP0[0] = c0[0]; bP0[1] = c0[1]; bP0[2] = c1[0]; bP0[3] = c1[1];
  bP0[4] = c2[0]; bP0[5] = c2[1]; bP0[6] = c3[0]; bP0[7] = c3[1];
  bP1[0] = c4[0]; bP1[1] = c4[1]; bP1[2] = c5[0]; bP1[3] = c5[1];
  bP1[4] = c6[0]; bP1[5] = c6[1]; bP1[6] = c7[0]; bP1[7] = c7[1];
  oa = __builtin_amdgcn_mfma_f32_32x32x16_f16(hc[0], bP0, oa, 0, 0, 0);
  oa = __builtin_amdgcn_mfma_f32_32x32x16_f16(hc[1], bP1, oa, 0, 0, 0);
  ob = __builtin_amdgcn_mfma_f32_32x32x16_f16(hc[2], bP0, ob, 0, 0, 0);
  ob = __builtin_amdgcn_mfma_f32_32x32x16_f16(hc[3], bP1, ob, 0, 0, 0);
}

__global__ __launch_bounds__(512, 2) void attn_mfma(
    const _Float16* __restrict__ fB, const _Float16* __restrict__ gB,
    const _Float16* __restrict__ hB, const float* __restrict__ v1N,
    const float* __restrict__ gamma_p, float* __restrict__ out) {
  __shared__ float obuf4[4][CO_][65];
  __shared__ float redM[8][64];
  __shared__ float redZ[8][64];

  const int id = blockIdx.x;                   // 256 blocks
  const int b = (id >> 1) & 3;                 // XCD pair -> batch
  const int mt = ((id & 1) << 5) | (id >> 3);  // 0..63
  const int m0 = mt * 64;
  const int t = threadIdx.x;
  const int lane = t & 63, s = t >> 6;
  const int m = lane & 31, hi = lane >> 5;
  const bool h1 = (hi != 0);

  const _Float16* fBase = fB + (size_t)b * L_ * CO_;
  const _Float16* hBase = hB + (size_t)b * CO_ * L_;

  // loop-invariant g B-frags for both m-halves
  const _Float16* g0 = gB + ((size_t)b * L_ + m0 + m) * CO_ + hi * 8;
  const _Float16* g1 = g0 + (size_t)32 * CO_;
  half8 gf0[4], gf1[4];
#pragma unroll
  for (int ks = 0; ks < 4; ++ks) {
    gf0[ks] = *(const half8*)(g0 + ks * 16);
    gf1[ks] = *(const half8*)(g1 + ks * 16);
  }

  f32x16 o0 = {}, o1 = {}, o2 = {}, o3 = {};
  float mx0 = -1e30f, Z0 = 0.f, mx1 = -1e30f, Z1 = 0.f;

  const int lbase = s * 512;
  half8 fc[2][4], hc[2][4];
  {  // initial load, step 0
    const _Float16* fr = fBase + (size_t)(lbase + m) * CO_ + hi * 8;
#pragma unroll
    for (int ks = 0; ks < 4; ++ks) fc[0][ks] = *(const half8*)(fr + ks * 16);
    const _Float16* hr = hBase + (size_t)m * L_ + lbase + hi * 8;
    const _Float16* hr2 = hr + (size_t)32 * L_;
    hc[0][0] = *(const half8*)(hr);
    hc[0][1] = *(const half8*)(hr + 16);
    hc[0][2] = *(const half8*)(hr2);
    hc[0][3] = *(const half8*)(hr2 + 16);
  }

#pragma unroll 2
  for (int stp = 0; stp < 16; ++stp) {
    const int cur = stp & 1, nxt = cur ^ 1;
    const int lb = lbase + stp * 32;
    {  // prefetch step+1 (last iter reads into adjacent ws buffers: harmless)
      const int ln = lb + 32;
      const _Float16* fr = fBase + (size_t)(ln + m) * CO_ + hi * 8;
#pragma unroll
      for (int ks = 0; ks < 4; ++ks) fc[nxt][ks] = *(const half8*)(fr + ks * 16);
      const _Float16* hr = hBase + (size_t)m * L_ + ln + hi * 8;
      const _Float16* hr2 = hr + (size_t)32 * L_;
      hc[nxt][0] = *(const half8*)(hr);
      hc[nxt][1] = *(const half8*)(hr + 16);
      hc[nxt][2] = *(const half8*)(hr2);
      hc[nxt][3] = *(const half8*)(hr2 + 16);
    }
    // S for both m-halves (scores in log2 units via Wq pre-scale)
    f32x16 S0 = {}, S1 = {};
#pragma unroll
    for (int ks = 0; ks < 4; ++ks) {
      S0 = __builtin_amdgcn_mfma_f32_32x32x16_f16(fc[cur][ks], gf0[ks], S0, 0, 0, 0);
      S1 = __builtin_amdgcn_mfma_f32_32x32x16_f16(fc[cur][ks], gf1[ks], S1, 0, 0, 0);
    }
    softmax_o(S0, mx0, Z0, o0, o1, hc[cur], h1);
    softmax_o(S1, mx1, Z1, o2, o3, hc[cur], h1);
  }

  // ---- merge the 8 l-partitions ----
  Z0 += __shfl_xor(Z0, 32, 64);
  Z1 += __shfl_xor(Z1, 32, 64);
  if (hi == 0) {
    redM[s][m] = mx0; redM[s][m + 32] = mx1;
    redZ[s][m] = Z0;  redZ[s][m + 32] = Z1;
  }
  __syncthreads();
  float M0 = redM[0][m], M1 = redM[0][m + 32];
#pragma unroll
  for (int i = 1; i < 8; ++i) {
    M0 = fmaxf(M0, redM[i][m]);
    M1 = fmaxf(M1, redM[i][m + 32]);
  }
  const float sc0 = EXP2(mx0 - M0);
  const float sc1 = EXP2(mx1 - M1);
  if (s < 4) {
#pragma unroll
    for (int r = 0; r < 16; ++r) {
      const int o = 4 * hi + 8 * (r >> 2) + (r & 3);
      obuf4[s][o][m] = sc0 * o0[r];
      obuf4[s][o + 32][m] = sc0 * o1[r];
      obuf4[s][o][m + 32] = sc1 * o2[r];
      obuf4[s][o + 32][m + 32] = sc1 * o3[r];
    }
  }
  __syncthreads();
  if (s >= 4) {
#pragma unroll
    for (int r = 0; r < 16; ++r) {
      const int o = 4 * hi + 8 * (r >> 2) + (r & 3);
      obuf4[s - 4][o][m] += sc0 * o0[r];
      obuf4[s - 4][o + 32][m] += sc0 * o1[r];
      obuf4[s - 4][o][m + 32] += sc1 * o2[r];
      obuf4[s - 4][o + 32][m + 32] += sc1 * o3[r];
    }
  }
  __syncthreads();

  // epilogue: out = gamma * O / Zt + v1
  const float gam = gamma_p[0];
  const int me = t & 63;   // m column
  const int og = t >> 6;   // 0..7
  float M = redM[0][me];
#pragma unroll
  for (int i = 1; i < 8; ++i) M = fmaxf(M, redM[i][me]);
  float Zt = 0.f;
#pragma unroll
  for (int i = 0; i < 8; ++i) Zt += EXP2(redM[i][me] - M) * redZ[i][me];
  const float inv = 1.0f / Zt;
#pragma unroll
  for (int i = 0; i < 8; ++i) {
    const int o = og * 8 + i;
    const float val = obuf4[0][o][me] + obuf4[1][o][me] +
                      obuf4[2][o][me] + obuf4[3][o][me];
    const size_t g = ((size_t)b * CO_ + o) * L_ + m0 + me;
    out[g] = gam * val * inv + v1N[g];
  }
}

extern "C" void kernel_launch(void* const* d_in, const int* in_sizes, int n_in,
                              void* d_out, int out_size, void* d_ws,
                              size_t ws_size, hipStream_t stream) {
  const float* x = (const float*)d_in[0];
  const float* Wq = (const float*)d_in[1];
  const float* Wk = (const float*)d_in[2];
  const float* Wv = (const float*)d_in[3];
  const float* Wv1 = (const float*)d_in[4];
  const float* gamma = (const float*)d_in[5];
  float* out = (float*)d_out;

  _Float16* Wf = (_Float16*)d_ws;
  _Float16* fB = Wf + (size_t)4 * CO_ * C_;
  _Float16* gB = fB + (size_t)B_ * L_ * CO_;
  _Float16* hB = gB + (size_t)B_ * L_ * CO_;
  float* v1N = (float*)(hB + (size_t)B_ * L_ * CO_);

  wcvt_kernel<<<dim3(12, 4), 256, 0, stream>>>(Wq, Wk, Wv, Wv1, Wf);
  proj_mfma<<<dim3(L_ / 32, B_), 256, 0, stream>>>(x, Wf, fB, gB, hB, v1N);
  attn_mfma<<<256, 512, 0, stream>>>(fB, gB, hB, v1N, gamma, out);
}

// Round 6
// 105.617 us; speedup vs baseline: 1.3811x; 1.1235x over previous
//
#include <hip/hip_runtime.h>
#include <math.h>

// Problem constants (fixed by the reference):
#define B_ 4
#define C_ 192
#define L_ 4096
#define CO_ 64
#define LOG2E 1.44269504088896340736f

using half8 = __attribute__((ext_vector_type(8))) _Float16;
using half4v = __attribute__((ext_vector_type(4))) _Float16;
using half2v = __attribute__((ext_vector_type(2))) _Float16;
using f32x16 = __attribute__((ext_vector_type(16))) float;

#if __has_builtin(__builtin_amdgcn_exp2f)
#define EXP2(x) __builtin_amdgcn_exp2f(x)
#else
#define EXP2(x) exp2f(x)
#endif

__device__ inline half2v pkrtz(float a, float b) {
  return __builtin_bit_cast(half2v, __builtin_amdgcn_cvt_pkrtz(a, b));
}

// ---------------------------------------------------------------------------
// ws layout (halfs unless noted; fully rewritten every call):
//   Wpack : [w][og][ks][lane]x8   4*2*12*64*8   = 49152   (96 KB, frag order)
//   fPack : [b][T][ks][lane]x8    4*128*4*64*8  = 2 MB    (A-frags of f, xLOG2E)
//   gB    : [b][m][o]             4*4096*64     = 2 MB    (B-frags of g)
//   hPack : [b][T][oh*2+ks][lane]x8             = 2 MB    (A-frags of h)
//   v1N   : [b][o][l] f32                       = 4 MB
// Fragment-packed layouts make every attn load lane-contiguous (8 cache
// lines per b128 instr instead of 32): attacks the measured TA line wall.
// ---------------------------------------------------------------------------

// Kernel 0: pack weights into MFMA fragment order, fp32 -> f16.
// Wpack[w][og][ks][lane][j] = W_w[og*32 + (lane&31)][ks*16 + (lane>>5)*8 + j]
// (times LOG2E for w==0). Serves as A-frag (w>=2) and B-frag (w<2, = W^T).
__global__ __launch_bounds__(256) void wpack_kernel(
    const float* __restrict__ Wq, const float* __restrict__ Wk,
    const float* __restrict__ Wv, const float* __restrict__ Wv1,
    _Float16* __restrict__ Wpack) {
  const int tid = blockIdx.x * 256 + threadIdx.x;  // 24*256 = 6144
  const int w = tid / 1536;
  const int rem = tid % 1536;
  const int og = rem / 768;
  const int ks = (rem % 768) / 64;
  const int lane = rem % 64;
  const float* src = (w == 0) ? Wq : (w == 1) ? Wk : (w == 2) ? Wv : Wv1;
  const float s = (w == 0) ? LOG2E : 1.0f;
  const int row = og * 32 + (lane & 31);
  const int col = ks * 16 + (lane >> 5) * 8;
  const float* p = src + row * C_ + col;
  const float4 a = *(const float4*)(p);
  const float4 c = *(const float4*)(p + 4);
  half8 o;
  half2v t;
  t = pkrtz(a.x * s, a.y * s); o[0] = t[0]; o[1] = t[1];
  t = pkrtz(a.z * s, a.w * s); o[2] = t[0]; o[3] = t[1];
  t = pkrtz(c.x * s, c.y * s); o[4] = t[0]; o[5] = t[1];
  t = pkrtz(c.z * s, c.w * s); o[6] = t[0]; o[7] = t[1];
  *(half8*)(Wpack + (size_t)tid * 8) = o;
}

// ---------------------------------------------------------------------------
// Kernel 1: projections via MFMA.  Grid (L/32=T, B), 256 thr (4 waves).
// x staged f32 [c][l] via global_load_lds; W frags from Wpack (8-line loads).
// Wave 0 (f): swapped operands D[l][o] -> LDS transpose -> fPack frag stores.
// Wave 1 (g): swapped operands -> direct [m][o] stores.
// Wave 2 (h): normal D[o][l] -> LDS transpose -> hPack frag stores.
// Wave 3 (v1): normal -> direct [o][l] f32 stores.
// ---------------------------------------------------------------------------
__global__ __launch_bounds__(256) void proj_mfma(
    const float* __restrict__ x, const _Float16* __restrict__ Wpack,
    _Float16* __restrict__ fPack, _Float16* __restrict__ gB,
    _Float16* __restrict__ hPack, float* __restrict__ v1N) {
  __shared__ __align__(16) float xs[C_ * 32];       // [c][l] rows of 128 B
  __shared__ __align__(16) _Float16 fl[32 * 72];    // wave-0 transpose buffer
  __shared__ __align__(16) _Float16 hl[64 * 40];    // wave-2 transpose buffer
  const int b = blockIdx.y, T = blockIdx.x, l0 = T * 32;
  const int t = threadIdx.x;
  const int lane = t & 63, w = t >> 6;
  const int m = lane & 31, hi = lane >> 5;

  {  // stage: wave w loads c-range [48w, 48w+48)
    const float* xb = x + (size_t)b * C_ * L_ + l0;
    const int c0 = w * 48;
#pragma unroll
    for (int i = 0; i < 6; ++i) {
      const int cc = c0 + i * 8;
      const float* gp = xb + (size_t)(cc + (lane >> 3)) * L_ + (lane & 7) * 4;
      __builtin_amdgcn_global_load_lds(
          (const __attribute__((address_space(1))) void*)gp,
          (__attribute__((address_space(3))) void*)&xs[cc * 32], 16, 0, 0);
    }
  }
  __syncthreads();

  // W frags (fragment-packed, lane-contiguous loads)
  const _Float16* Wp = Wpack + (size_t)w * 1536 * 8;
  half8 wf[2][12];
#pragma unroll
  for (int og = 0; og < 2; ++og)
#pragma unroll
    for (int ks = 0; ks < 12; ++ks)
      wf[og][ks] = *(const half8*)(Wp + ((size_t)(og * 12 + ks) * 64 + lane) * 8);

  if (w < 2) {
    // D[l][o] = x^T W^T : A = x^T rows l, B = W^T cols o.
    f32x16 acc0 = {}, acc1 = {};
#pragma unroll
    for (int ks = 0; ks < 12; ++ks) {
      const float* xr = &xs[(ks * 16 + hi * 8) * 32 + m];
      half8 aF;
#pragma unroll
      for (int e = 0; e < 8; e += 2) {
        const half2v hp = pkrtz(xr[e * 32], xr[(e + 1) * 32]);
        aF[e] = hp[0]; aF[e + 1] = hp[1];
      }
      acc0 = __builtin_amdgcn_mfma_f32_32x32x16_f16(aF, wf[0][ks], acc0, 0, 0, 0);
      acc1 = __builtin_amdgcn_mfma_f32_32x32x16_f16(aF, wf[1][ks], acc1, 0, 0, 0);
    }
    if (w == 0) {
      // transpose via LDS, then fragment-packed stores (lane-contiguous)
#pragma unroll
      for (int r = 0; r < 16; ++r) {
        const int l = 4 * hi + 8 * (r >> 2) + (r & 3);
        fl[l * 72 + m] = (_Float16)acc0[r];
        fl[l * 72 + 32 + m] = (_Float16)acc1[r];
      }
      _Float16* dst = fPack + (size_t)b * L_ * CO_ + (size_t)T * 4 * 64 * 8;
#pragma unroll
      for (int ks = 0; ks < 4; ++ks) {
        const half8 v = *(const half8*)&fl[(lane & 31) * 72 + ks * 16 + (lane >> 5) * 8];
        *(half8*)(dst + ((size_t)ks * 64 + lane) * 8) = v;
      }
    } else {
      _Float16* dst = gB;
#pragma unroll
      for (int r = 0; r < 16; ++r) {
        const int lrow = 4 * hi + 8 * (r >> 2) + (r & 3);
        _Float16* row = dst + ((size_t)b * L_ + l0 + lrow) * CO_;
        row[m] = (_Float16)acc0[r];
        row[32 + m] = (_Float16)acc1[r];
      }
    }
  } else {
    // D[o][l] = W x : A = W rows o, B = x cols l.
    const int lg = l0 + m;
    for (int oh = 0; oh < 2; ++oh) {
      f32x16 acc = {};
#pragma unroll
      for (int ks = 0; ks < 12; ++ks) {
        const float* xr = &xs[(16 * ks + 8 * hi) * 32 + m];
        half8 bF;
#pragma unroll
        for (int e = 0; e < 8; e += 2) {
          const half2v hp = pkrtz(xr[e * 32], xr[(e + 1) * 32]);
          bF[e] = hp[0]; bF[e + 1] = hp[1];
        }
        acc = __builtin_amdgcn_mfma_f32_32x32x16_f16(wf[oh][ks], bF, acc, 0, 0, 0);
      }
      if (w == 2) {
#pragma unroll
        for (int r = 0; r < 16; ++r) {
          const int o = 32 * oh + 4 * hi + 8 * (r >> 2) + (r & 3);
          hl[o * 40 + m] = (_Float16)acc[r];
        }
      } else {
#pragma unroll
        for (int r = 0; r < 16; ++r) {
          const int o = 32 * oh + 4 * hi + 8 * (r >> 2) + (r & 3);
          v1N[((size_t)b * CO_ + o) * L_ + lg] = acc[r];
        }
      }
    }
    if (w == 2) {  // fragment-packed stores
      _Float16* dst = hPack + (size_t)b * L_ * CO_ + (size_t)T * 4 * 64 * 8;
#pragma unroll
      for (int j = 0; j < 4; ++j) {  // j = oh*2 + ks
        const int oh2 = j >> 1, ks2 = j & 1;
        const half8 v = *(const half8*)&hl[(32 * oh2 + (lane & 31)) * 40 +
                                           ks2 * 16 + (lane >> 5) * 8];
        *(half8*)(dst + ((size_t)j * 64 + lane) * 8) = v;
      }
    }
  }
}

// ---------------------------------------------------------------------------
// Kernel 2: flash attention, fragment-packed loads (8 lines/instr).
// 256 blocks (1/CU; XCD pair -> batch), 512 thr = 8 waves.
// Wave s: l-partition [512s, 512s+512), 16 steps of 32 l x 64 m.
// P transform via per-wave LDS (4 ds_write_b64 + 2 ds_read_b128, stride 40).
// ---------------------------------------------------------------------------
__device__ __forceinline__ void softmax_o(const f32x16& S, float& mx, float& Z,
                                          f32x16& oa, f32x16& ob,
                                          const half8* hc, _Float16* Pw,
                                          int m, int hi) {
  float tmax = S[0];
#pragma unroll
  for (int r = 1; r < 16; ++r) tmax = fmaxf(tmax, S[r]);
  tmax = fmaxf(tmax, __shfl_xor(tmax, 32, 64));
  if (__any(tmax > mx)) {
    const float mnew = fmaxf(mx, tmax);
    const float corr = EXP2(mx - mnew);
    mx = mnew;
    Z *= corr;
#pragma unroll
    for (int r = 0; r < 16; ++r) { oa[r] *= corr; ob[r] *= corr; }
  }
  float zl = 0.f;
#pragma unroll
  for (int u = 0; u < 4; ++u) {
    const float p0 = EXP2(S[4 * u + 0] - mx);
    const float p1 = EXP2(S[4 * u + 1] - mx);
    const float p2 = EXP2(S[4 * u + 2] - mx);
    const float p3 = EXP2(S[4 * u + 3] - mx);
    zl += (p0 + p1) + (p2 + p3);
    const half2v lo = pkrtz(p0, p1);
    const half2v hi2 = pkrtz(p2, p3);
    half4v w4; w4[0] = lo[0]; w4[1] = lo[1]; w4[2] = hi2[0]; w4[3] = hi2[1];
    // P[m-col][l] row stride 40 halfs; l = 4*hi + 8*u + {0..3}
    *(half4v*)(Pw + m * 40 + 4 * hi + 8 * u) = w4;
  }
  Z += zl;  // per-half partial; cross-half shfl deferred to merge
  const half8 bP0 = *(const half8*)(Pw + m * 40 + 8 * hi);       // k=0..15
  const half8 bP1 = *(const half8*)(Pw + m * 40 + 16 + 8 * hi);  // k=16..31
  oa = __builtin_amdgcn_mfma_f32_32x32x16_f16(hc[0], bP0, oa, 0, 0, 0);
  oa = __builtin_amdgcn_mfma_f32_32x32x16_f16(hc[1], bP1, oa, 0, 0, 0);
  ob = __builtin_amdgcn_mfma_f32_32x32x16_f16(hc[2], bP0, ob, 0, 0, 0);
  ob = __builtin_amdgcn_mfma_f32_32x32x16_f16(hc[3], bP1, ob, 0, 0, 0);
}

__global__ __launch_bounds__(512, 2) void attn_mfma(
    const _Float16* __restrict__ fPack, const _Float16* __restrict__ gB,
    const _Float16* __restrict__ hPack, const float* __restrict__ v1N,
    const float* __restrict__ gamma_p, float* __restrict__ out) {
  __shared__ __align__(16) _Float16 Pl[8][32 * 40];
  __shared__ float obuf4[4][CO_][65];
  __shared__ float redM[8][64];
  __shared__ float redZ[8][64];

  const int id = blockIdx.x;                   // 256 blocks
  const int b = (id >> 1) & 3;                 // XCD pair -> batch
  const int mt = ((id & 1) << 5) | (id >> 3);  // 0..63
  const int m0 = mt * 64;
  const int t = threadIdx.x;
  const int lane = t & 63, s = t >> 6;
  const int m = lane & 31, hi = lane >> 5;

  const _Float16* fT = fPack + (size_t)b * L_ * CO_;
  const _Float16* hT = hPack + (size_t)b * L_ * CO_;
  _Float16* Pw = &Pl[s][0];

  // loop-invariant g B-frags for both m-halves
  const _Float16* g0 = gB + ((size_t)b * L_ + m0 + m) * CO_ + hi * 8;
  const _Float16* g1 = g0 + (size_t)32 * CO_;
  half8 gf0[4], gf1[4];
#pragma unroll
  for (int ks = 0; ks < 4; ++ks) {
    gf0[ks] = *(const half8*)(g0 + ks * 16);
    gf1[ks] = *(const half8*)(g1 + ks * 16);
  }

  f32x16 o0 = {}, o1 = {}, o2 = {}, o3 = {};
  float mx0 = -1e30f, Z0 = 0.f, mx1 = -1e30f, Z1 = 0.f;

  const int T0 = s * 16;
  half8 fc[2][4], hc[2][4];
  {  // initial frags, step 0 (lane-contiguous 1 KB loads)
    const _Float16* fp = fT + ((size_t)T0 * 4 * 64 + lane) * 8;
    const _Float16* hp = hT + ((size_t)T0 * 4 * 64 + lane) * 8;
#pragma unroll
    for (int ks = 0; ks < 4; ++ks) {
      fc[0][ks] = *(const half8*)(fp + (size_t)ks * 64 * 8);
      hc[0][ks] = *(const half8*)(hp + (size_t)ks * 64 * 8);
    }
  }

#pragma unroll 2
  for (int stp = 0; stp < 16; ++stp) {
    const int cur = stp & 1, nxt = cur ^ 1;
    {  // prefetch step+1 (tail reads run into the next ws buffer: harmless)
      const int Tn = T0 + stp + 1;
      const _Float16* fp = fT + ((size_t)Tn * 4 * 64 + lane) * 8;
      const _Float16* hp = hT + ((size_t)Tn * 4 * 64 + lane) * 8;
#pragma unroll
      for (int ks = 0; ks < 4; ++ks) {
        fc[nxt][ks] = *(const half8*)(fp + (size_t)ks * 64 * 8);
        hc[nxt][ks] = *(const half8*)(hp + (size_t)ks * 64 * 8);
      }
    }
    // S for both m-halves (scores in log2 units via Wq pre-scale)
    f32x16 S0 = {}, S1 = {};
#pragma unroll
    for (int ks = 0; ks < 4; ++ks) {
      S0 = __builtin_amdgcn_mfma_f32_32x32x16_f16(fc[cur][ks], gf0[ks], S0, 0, 0, 0);
      S1 = __builtin_amdgcn_mfma_f32_32x32x16_f16(fc[cur][ks], gf1[ks], S1, 0, 0, 0);
    }
    softmax_o(S0, mx0, Z0, o0, o1, hc[cur], Pw, m, hi);
    softmax_o(S1, mx1, Z1, o2, o3, hc[cur], Pw, m, hi);
  }

  // ---- merge the 8 l-partitions ----
  Z0 += __shfl_xor(Z0, 32, 64);
  Z1 += __shfl_xor(Z1, 32, 64);
  if (hi == 0) {
    redM[s][m] = mx0; redM[s][m + 32] = mx1;
    redZ[s][m] = Z0;  redZ[s][m + 32] = Z1;
  }
  __syncthreads();
  float M0 = redM[0][m], M1 = redM[0][m + 32];
#pragma unroll
  for (int i = 1; i < 8; ++i) {
    M0 = fmaxf(M0, redM[i][m]);
    M1 = fmaxf(M1, redM[i][m + 32]);
  }
  const float sc0 = EXP2(mx0 - M0);
  const float sc1 = EXP2(mx1 - M1);
  if (s < 4) {
#pragma unroll
    for (int r = 0; r < 16; ++r) {
      const int o = 4 * hi + 8 * (r >> 2) + (r & 3);
      obuf4[s][o][m] = sc0 * o0[r];
      obuf4[s][o + 32][m] = sc0 * o1[r];
      obuf4[s][o][m + 32] = sc1 * o2[r];
      obuf4[s][o + 32][m + 32] = sc1 * o3[r];
    }
  }
  __syncthreads();
  if (s >= 4) {
#pragma unroll
    for (int r = 0; r < 16; ++r) {
      const int o = 4 * hi + 8 * (r >> 2) + (r & 3);
      obuf4[s - 4][o][m] += sc0 * o0[r];
      obuf4[s - 4][o + 32][m] += sc0 * o1[r];
      obuf4[s - 4][o][m + 32] += sc1 * o2[r];
      obuf4[s - 4][o + 32][m + 32] += sc1 * o3[r];
    }
  }
  __syncthreads();

  // epilogue: out = gamma * O / Zt + v1
  const float gam = gamma_p[0];
  const int me = t & 63;   // m column
  const int og = t >> 6;   // 0..7
  float M = redM[0][me];
#pragma unroll
  for (int i = 1; i < 8; ++i) M = fmaxf(M, redM[i][me]);
  float Zt = 0.f;
#pragma unroll
  for (int i = 0; i < 8; ++i) Zt += EXP2(redM[i][me] - M) * redZ[i][me];
  const float inv = 1.0f / Zt;
#pragma unroll
  for (int i = 0; i < 8; ++i) {
    const int o = og * 8 + i;
    const float val = obuf4[0][o][me] + obuf4[1][o][me] +
                      obuf4[2][o][me] + obuf4[3][o][me];
    const size_t g = ((size_t)b * CO_ + o) * L_ + m0 + me;
    out[g] = gam * val * inv + v1N[g];
  }
}

extern "C" void kernel_launch(void* const* d_in, const int* in_sizes, int n_in,
                              void* d_out, int out_size, void* d_ws,
                              size_t ws_size, hipStream_t stream) {
  const float* x = (const float*)d_in[0];
  const float* Wq = (const float*)d_in[1];
  const float* Wk = (const float*)d_in[2];
  const float* Wv = (const float*)d_in[3];
  const float* Wv1 = (const float*)d_in[4];
  const float* gamma = (const float*)d_in[5];
  float* out = (float*)d_out;

  _Float16* Wpack = (_Float16*)d_ws;                    // 49152 halfs
  _Float16* fPack = Wpack + (size_t)4 * 1536 * 8;
  _Float16* gB = fPack + (size_t)B_ * L_ * CO_;
  _Float16* hPack = gB + (size_t)B_ * L_ * CO_;
  float* v1N = (float*)(hPack + (size_t)B_ * L_ * CO_);

  wpack_kernel<<<24, 256, 0, stream>>>(Wq, Wk, Wv, Wv1, Wpack);
  proj_mfma<<<dim3(L_ / 32, B_), 256, 0, stream>>>(x, Wpack, fPack, gB, hPack, v1N);
  attn_mfma<<<256, 512, 0, stream>>>(fPack, gB, hPack, v1N, gamma, out);
}